// Round 8
// baseline (830.368 us; speedup 1.0000x reference)
//
#include <hip/hip_runtime.h>
#include <hip/hip_bf16.h>

typedef __hip_bfloat16 BF;
typedef __bf16 v8bf __attribute__((ext_vector_type(8)));
typedef float v4f __attribute__((ext_vector_type(4)));

constexpr int SEQ = 2048;
constexpr int DIMC = 512;
constexpr int BSZ = 8;

// flags for gemm_bt
#define GF_RELU 1
#define GF_CAUSAL 2   // mask col>row with 0, skip tiles entirely above diagonal
#define GF_KCAP 4     // limit K-loop to m0+256 (causal reduction cap)
#define GF_QKV 8      // route columns: 0-511->outB(q), 512-1023->outF-as-BF(k), 1024-1535->outV(v)

__device__ __forceinline__ void async16(BF* lds, const BF* g) {
  __builtin_amdgcn_global_load_lds(
      (const __attribute__((address_space(1))) void*)g,
      (__attribute__((address_space(3))) void*)lds,
      16, 0, 0);
}

// C[M,N] = A[M,K] @ W[N,K]^T (both K-contiguous), bf16 in, fp32 accum.
// R8: 256x256 tile (halves staged bytes vs 128x128 — staging-BW-bound at
// ~4.2 TB/s per R1-R7 ledger), 512 threads = 8 waves x (64x128) wave tiles,
// BK=32, single-buffered 32 KB LDS, XOR swizzle (conflicts=0 since R2).
// 128 AGPR acc + ~80 VGPR -> 2 waves/SIMD, 2 blocks/CU.
__global__ __launch_bounds__(512, 2) void gemm_bt(
    const BF* __restrict__ A, const BF* __restrict__ W, const float* __restrict__ bias,
    BF* __restrict__ outB, float* __restrict__ outF, BF* __restrict__ outV,
    int M, int N, int K,
    long long strideA, long long strideW, long long strideC,
    float scale, int flags)
{
  const int m0 = blockIdx.y * 256;
  const int n0 = blockIdx.x * 256;
  if ((flags & GF_CAUSAL) && n0 > m0) return;  // tile fully above diagonal

  const int z = blockIdx.z;
  const BF* __restrict__ Ab = A + (size_t)z * strideA;
  const BF* __restrict__ Wb = W + (size_t)z * strideW;
  const size_t coff = (size_t)z * strideC;

  const int tid = threadIdx.x;
  const int w = tid >> 6;            // 0..7
  const int lane = tid & 63;
  const int lane15 = lane & 15;
  const int quad = lane >> 4;
  const int wrow = w >> 1, wcol = w & 1;   // wave tile: rows [wrow*64,+64) x cols [wcol*128,+128)
  // staging: lane -> (row rl, kslot lane&3); slot q holds global kgroup q^((rl>>1)&3)
  const int rl = lane >> 2;
  const int clsw = ((lane & 3) ^ ((rl >> 1) & 3)) << 3;  // swizzled k-offset (elems)

  __shared__ __align__(16) BF sA[256 * 32];  // 16 KB
  __shared__ __align__(16) BF sW[256 * 32];  // 16 KB

  v4f acc[4][8];
  {
    v4f zero = {0.f, 0.f, 0.f, 0.f};
#pragma unroll
    for (int a = 0; a < 4; ++a)
#pragma unroll
      for (int b = 0; b < 8; ++b) acc[a][b] = zero;
  }

  int Klim = K;
  if (flags & GF_KCAP) { int kc = m0 + 256; if (kc < Klim) Klim = kc; }
  const int ksteps = Klim >> 5;

  const int sw = quad ^ ((lane15 >> 1) & 3);  // read-side swizzle

  for (int kk = 0; kk < ksteps; ++kk) {
    const int k0 = kk << 5;
#pragma unroll
    for (int i = 0; i < 2; ++i) {
      const int r0 = w * 32 + i * 16;  // wave-uniform 16-row chunk (8 waves cover 256 rows)
      async16(&sA[r0 * 32], Ab + (size_t)(m0 + r0 + rl) * K + (k0 + clsw));
      async16(&sW[r0 * 32], Wb + (size_t)(n0 + r0 + rl) * K + (k0 + clsw));
    }
    __syncthreads();  // drains vmcnt(0): all slabs resident

    v8bf aF[4], wF[8];
    const v8bf* sAv = (const v8bf*)sA;
    const v8bf* sWv = (const v8bf*)sW;
#pragma unroll
    for (int t = 0; t < 4; ++t)
      aF[t] = sAv[(wrow * 64 + t * 16 + lane15) * 4 + sw];
#pragma unroll
    for (int t = 0; t < 8; ++t)
      wF[t] = sWv[(wcol * 128 + t * 16 + lane15) * 4 + sw];
#pragma unroll
    for (int mt = 0; mt < 4; ++mt)
#pragma unroll
      for (int nt = 0; nt < 8; ++nt)
        acc[mt][nt] = __builtin_amdgcn_mfma_f32_16x16x32_bf16(aF[mt], wF[nt], acc[mt][nt], 0, 0, 0);
    __syncthreads();  // reads done before next stage overwrites
  }

  // epilogue: C/D layout col=lane&15, row=quad*4+i
#pragma unroll
  for (int mt = 0; mt < 4; ++mt) {
    const int rb = m0 + wrow * 64 + mt * 16 + quad * 4;
#pragma unroll
    for (int nt = 0; nt < 8; ++nt) {
      const int cg = n0 + wcol * 128 + nt * 16 + lane15;
      const float bv = bias ? bias[cg] : 0.0f;
#pragma unroll
      for (int i = 0; i < 4; ++i) {
        const int rg = rb + i;
        float v = acc[mt][nt][i] * scale + bv;
        if ((flags & GF_RELU) && v < 0.f) v = 0.f;
        if ((flags & GF_CAUSAL) && cg > rg) v = 0.f;
        if (flags & GF_QKV) {
          const BF b = __float2bfloat16(v);
          if (cg < 512) outB[(size_t)rg * 512 + cg] = b;
          else if (cg < 1024) ((BF*)outF)[(size_t)rg * 512 + (cg - 512)] = b;
          else outV[(size_t)rg * 512 + (cg - 1024)] = b;
        } else {
          if (outB) outB[coff + (size_t)rg * N + cg] = __float2bfloat16(v);
          if (outF) outF[coff + (size_t)rg * N + cg] = v;
        }
      }
    }
  }
}

// x[b,s,:] = concat(emb_table[idx[b,s]][0:448], feats[b,s,0:64]) -> bf16
__global__ void gather_kernel(const int* __restrict__ seq, const float* __restrict__ feats,
                              const float* __restrict__ emb, BF* __restrict__ xb) {
  const int row = blockIdx.x;  // b*SEQ + s
  const int t = threadIdx.x;
  const int idx = seq[row];
  BF* xr = xb + (size_t)row * DIMC;
  if (t < 224) {
    const float2 e = *(const float2*)(emb + (size_t)idx * 448 + t * 2);
    xr[t * 2] = __float2bfloat16(e.x);
    xr[t * 2 + 1] = __float2bfloat16(e.y);
  } else {
    const int j = (t - 224) * 2;
    const float2 f = *(const float2*)(feats + (size_t)row * 64 + j);
    xr[448 + j] = __float2bfloat16(f.x);
    xr[448 + j + 1] = __float2bfloat16(f.y);
  }
}

// one-shot weight prep: wb = bf16(W1|W2), wqkv = bf16 packed [2][1536][512], bqkv packed bias
__global__ void prep_kernel(const float* __restrict__ W1, const float* __restrict__ W2,
                            const float* __restrict__ Wq, const float* __restrict__ Wk,
                            const float* __restrict__ Wv, const float* __restrict__ bq,
                            const float* __restrict__ bk, const float* __restrict__ bv,
                            BF* __restrict__ wb, BF* __restrict__ wqkv, float* __restrict__ bqkv) {
  const int t = blockIdx.x * 256 + threadIdx.x;  // 655,360 threads
  const long long i = (long long)t * 4;
  float4 v;
  BF* o;
  if (i < 1048576) {  // wb: W1 | W2 (each 524,288)
    v = (i < 524288) ? *(const float4*)(W1 + i) : *(const float4*)(W2 + (i - 524288));
    o = wb + i;
  } else {            // wqkv: [l][q|k|v row][col]
    const long long j = i - 1048576;
    const int l = j >= 786432 ? 1 : 0;
    const long long rem = j - (long long)l * 786432;
    const int r = (int)(rem >> 9), c = (int)(rem & 511);
    const float* s = (r < 512) ? Wq : (r < 1024 ? Wk : Wv);
    v = *(const float4*)(s + (size_t)l * 262144 + (size_t)(r & 511) * 512 + c);
    o = wqkv + j;
  }
  o[0] = __float2bfloat16(v.x); o[1] = __float2bfloat16(v.y);
  o[2] = __float2bfloat16(v.z); o[3] = __float2bfloat16(v.w);
  if (t < 768) {  // bqkv: 3072 elems
#pragma unroll
    for (int e = t * 4; e < t * 4 + 4; ++e) {
      const int l = e / 1536, r = e % 1536;
      const float* s = (r < 512) ? bq : (r < 1024 ? bk : bv);
      bqkv[e] = s[l * 512 + (r & 511)];
    }
  }
}

// vtmp [b][s][512] bf16 -> vt [b][512][s] bf16, 64x64 LDS tiles
__global__ void transpose_kernel(const BF* __restrict__ in, BF* __restrict__ out) {
  __shared__ BF t[64][65];
  const int b = blockIdx.z;
  const int s0 = blockIdx.x * 64, d0 = blockIdx.y * 64;
  const int dx = threadIdx.x & 63, ry = threadIdx.x >> 6;  // ry in 0..3
  const BF* ib = in + ((size_t)b * SEQ + s0) * DIMC + d0;
  BF* ob = out + ((size_t)b * DIMC + d0) * SEQ + s0;
#pragma unroll
  for (int i = 0; i < 16; ++i)
    t[ry + i * 4][dx] = ib[(size_t)(ry + i * 4) * DIMC + dx];
  __syncthreads();
#pragma unroll
  for (int i = 0; i < 16; ++i)
    ob[(size_t)(ry + i * 4) * SEQ + dx] = t[dx][ry + i * 4];
}

// ---- seq-norm, 3-pass streaming ----
__global__ void seqsum_kernel(const float* __restrict__ h, float* __restrict__ part) {
  const int b = blockIdx.y, ch = blockIdx.x;  // 32 chunks of 64 rows
  const int t = threadIdx.x;
  const int half = t >> 7, cidx = t & 127;    // 128 float4-columns
  const float* hb = h + ((size_t)b * SEQ + ch * 64 + half * 32) * DIMC + cidx * 4;
  float4 sum = {0.f, 0.f, 0.f, 0.f}, sq = {0.f, 0.f, 0.f, 0.f};
#pragma unroll 4
  for (int r = 0; r < 32; ++r) {
    const float4 v = *(const float4*)(hb + (size_t)r * DIMC);
    sum.x += v.x; sum.y += v.y; sum.z += v.z; sum.w += v.w;
    sq.x += v.x * v.x; sq.y += v.y * v.y; sq.z += v.z * v.z; sq.w += v.w * v.w;
  }
  __shared__ float4 lsum[256], lsq[256];
  lsum[t] = sum; lsq[t] = sq;
  __syncthreads();
  if (t < 128) {
    const float4 s2 = lsum[t + 128], q2 = lsq[t + 128];
    sum.x += s2.x; sum.y += s2.y; sum.z += s2.z; sum.w += s2.w;
    sq.x += q2.x; sq.y += q2.y; sq.z += q2.z; sq.w += q2.w;
    float* ps = part + (size_t)(b * 32 + ch) * 1024;
    *(float4*)(ps + cidx * 4) = sum;
    *(float4*)(ps + 512 + cidx * 4) = sq;
  }
}

__global__ void seqstat_kernel(const float* __restrict__ part, float2* __restrict__ stat) {
  const int i = blockIdx.x * 256 + threadIdx.x;  // 4096 = 8*512
  const int b = i >> 9, d = i & 511;
  const float* p = part + (size_t)b * 32 * 1024 + d;
  float s = 0.f, q = 0.f;
#pragma unroll 8
  for (int c = 0; c < 32; ++c) { s += p[c * 1024]; q += p[c * 1024 + 512]; }
  const float mean = s / SEQ;
  float var = (q - mean * s) / (SEQ - 1);
  if (var < 0.f) var = 0.f;
  stat[i] = make_float2(mean, 1.0f / (sqrtf(var) + 2e-5f));
}

__global__ void seqapply_kernel(const float* __restrict__ h, const float2* __restrict__ stat,
                                BF* __restrict__ out) {
  const size_t i = ((size_t)blockIdx.x * 256 + threadIdx.x) * 4;  // 16,777,216 elems
  const int b = (int)(i >> 20);                                   // SEQ*DIMC = 2^20
  const int d = (int)(i & 511);
  const float4 v = *(const float4*)(h + i);
  const float2* sb = stat + (b << 9) + d;
  const float4 s01 = *(const float4*)(sb);
  const float4 s23 = *(const float4*)(sb + 2);
  out[i]     = __float2bfloat16((v.x - s01.x) * s01.y);
  out[i + 1] = __float2bfloat16((v.y - s01.z) * s01.w);
  out[i + 2] = __float2bfloat16((v.z - s23.x) * s23.y);
  out[i + 3] = __float2bfloat16((v.w - s23.z) * s23.w);
}

__global__ void final_kernel(const float* __restrict__ h32, float* __restrict__ out) {
  const int i = blockIdx.x * 256 + threadIdx.x;  // 0..4095
  const int b = i >> 9, d = i & 511;
  out[i] = h32[((size_t)b * SEQ + (SEQ - 1)) * DIMC + d];
}

extern "C" void kernel_launch(void* const* d_in, const int* in_sizes, int n_in,
                              void* d_out, int out_size, void* d_ws, size_t ws_size,
                              hipStream_t stream) {
  const int* seq = (const int*)d_in[0];
  const float* feats = (const float*)d_in[1];
  const float* emb = (const float*)d_in[2];
  const float* Wq = (const float*)d_in[3];
  const float* bq = (const float*)d_in[4];
  const float* Wk = (const float*)d_in[5];
  const float* bk = (const float*)d_in[6];
  const float* Wv = (const float*)d_in[7];
  const float* bv = (const float*)d_in[8];
  const float* W1 = (const float*)d_in[9];
  const float* b1 = (const float*)d_in[10];
  const float* W2 = (const float*)d_in[11];
  const float* b2 = (const float*)d_in[12];
  float* out = (float*)d_out;

  char* ws = (char*)d_ws;
  const size_t MB = 1024 * 1024;
  BF* xb = (BF*)(ws);                   // 16 MB: x bf16 (also x_next)
  BF* qb = (BF*)(ws + 16 * MB);         // 16 MB: q bf16 (also hn)
  BF* kb = (BF*)(ws + 32 * MB);         // 16 MB: k bf16 (also f1)
  BF* vt = (BF*)(ws + 48 * MB);         // 16 MB: v^T bf16 [b][d][s]
  float* h32 = (float*)(ws + 64 * MB);  // 32 MB: attention out fp32 (also final fp32)
  BF* vtmp = (BF*)(ws + 64 * MB);       // overlays h32 head: v [b][s][d] before transpose
  BF* sc = (BF*)(ws + 96 * MB);         // 64 MB: scores bf16 [b][s][n]
  BF* wb = (BF*)(ws + 160 * MB);        // 2 MB: bf16 W1,W2
  BF* wqkv = (BF*)(ws + 162 * MB);      // 3 MB: bf16 packed qkv weights [2][1536][512]
  float* bqkv = (float*)(ws + 166 * MB);// 12 KB: packed qkv bias [2][1536]
  float* part = (float*)(ws + 167 * MB);// 1 MB: seqnorm partials [8][32][2][512]
  float2* stat = (float2*)(ws + 168 * MB); // 32 KB: seqnorm mean/rstd [8][512]

  const int WT = 2 * 512 * 512;
  prep_kernel<<<2560, 256, 0, stream>>>(W1, W2, Wq, Wk, Wv, bq, bk, bv, wb, wqkv, bqkv);
  gather_kernel<<<BSZ * SEQ, 256, 0, stream>>>(seq, feats, emb, xb);

  const float attn_scale = 0.04419417382415922f;  // 1/sqrt(512)
  const dim3 gblk(512);
  const dim3 blk(256);

  for (int l = 0; l < 2; ++l) {
    const BF* W1B = wb + (size_t)l * 262144;
    const BF* W2B = wb + (size_t)WT + (size_t)l * 262144;

    // fused q|k|v projection: M=16384, N=1536, K=512
    gemm_bt<<<dim3(6, 64, 1), gblk, 0, stream>>>(xb, wqkv + (size_t)l * 786432, bqkv + l * 1536,
        qb, (float*)kb, vtmp, 16384, 1536, 512, 0, 0, 0, 1.0f, GF_QKV);
    // coalesced v transpose -> vt [b][d][s]
    transpose_kernel<<<dim3(32, 8, 8), blk, 0, stream>>>(vtmp, vt);
    // scores = tril(q @ k^T) * scale, per batch (M=N=2048, K=512)
    gemm_bt<<<dim3(8, 8, 8), gblk, 0, stream>>>(qb, kb, nullptr, sc, nullptr, nullptr,
        2048, 2048, 512,
        (long long)SEQ * DIMC, (long long)SEQ * DIMC, (long long)SEQ * SEQ,
        attn_scale, GF_CAUSAL);
    // h = scores @ v, per batch (M=2048, N=512, K=2048 capped at diagonal)
    gemm_bt<<<dim3(2, 8, 8), gblk, 0, stream>>>(sc, vt, nullptr, nullptr, h32, nullptr,
        2048, 512, 2048,
        (long long)SEQ * SEQ, (long long)DIMC * SEQ, (long long)SEQ * DIMC,
        1.0f, GF_KCAP);
    // seq-norm over s (3-pass streaming) -> bf16 into qb
    seqsum_kernel<<<dim3(32, 8), blk, 0, stream>>>(h32, part);
    seqstat_kernel<<<16, 256, 0, stream>>>(part, stat);
    seqapply_kernel<<<16384, 256, 0, stream>>>(h32, stat, qb);
    // ffn1 = relu(hn @ W1^T + b1) -> kb
    gemm_bt<<<dim3(2, 64, 1), gblk, 0, stream>>>(qb, W1B, b1 + l * 512, kb, nullptr, nullptr,
        16384, 512, 512, 0, 0, 0, 1.0f, GF_RELU);
    // x_next = f1 @ W2^T + b2 -> xb (bf16); final block also fp32 -> h32
    gemm_bt<<<dim3(2, 64, 1), gblk, 0, stream>>>(kb, W2B, b2 + l * 512, xb,
        (l == 1) ? h32 : nullptr, nullptr, 16384, 512, 512, 0, 0, 0, 1.0f, 0);
  }

  final_kernel<<<16, 256, 0, stream>>>(h32, out);
}

// Round 9
// 576.352 us; speedup vs baseline: 1.4407x; 1.4407x over previous
//
#include <hip/hip_runtime.h>
#include <hip/hip_bf16.h>

typedef __hip_bfloat16 BF;
typedef __bf16 v8bf __attribute__((ext_vector_type(8)));
typedef float v4f __attribute__((ext_vector_type(4)));

constexpr int SEQ = 2048;
constexpr int DIMC = 512;
constexpr int BSZ = 8;

// flags for gemm_bt
#define GF_RELU 1
#define GF_CAUSAL 2   // mask col>row with 0, skip tiles entirely above diagonal
#define GF_KCAP 4     // limit K-loop to m0+128 (causal reduction cap)
#define GF_QKV 8      // route columns: 0-511->outB(q), 512-1023->outF-as-BF(k), 1024-1535->outV(v)
#define GF_BATCH8 16  // 1D grid, batch z = id&7 (XCD-pinned batches)

// s_waitcnt immediates (gfx9: vmcnt[3:0]+[15:14], expcnt[6:4]=7 nowait, lgkmcnt[11:8]=0xF nowait)
#define WAIT_VM4 0x0F74
#define WAIT_VM0 0x0F70

__device__ __forceinline__ void async16(BF* lds, const BF* g) {
  __builtin_amdgcn_global_load_lds(
      (const __attribute__((address_space(1))) void*)g,
      (__attribute__((address_space(3))) void*)lds,
      16, 0, 0);
}

// C[M,N] = A[M,K] @ W[N,K]^T (both K-contiguous), bf16 in, fp32 accum.
// R7 body (best measured: 637 µs total): 128x128 tile, BK=32, dbuf LDS
// 32 KB, prefetch dist-1, vmcnt(4)-gated barriers, XOR swizzle
// (conflicts=0), __launch_bounds__(256,4).
// R9: 1D grid + XCD-locality decode. Workgroups round-robin XCDs by
// linear id (id&7). BATCH8: batch = id&7 -> one batch's q/k (4 MB) stays
// in one XCD's L2. Else: m-panel = (id&7)+8*((id>>3)&15), n = id>>7 ->
// each XCD owns 16 x-panels (2 MB) + W (<=1.5 MB), L2-resident.
__global__ __launch_bounds__(256, 4) void gemm_bt(
    const BF* __restrict__ A, const BF* __restrict__ W, const float* __restrict__ bias,
    BF* __restrict__ outB, float* __restrict__ outF, BF* __restrict__ outV,
    int M, int N, int K, int nbx,
    long long strideA, long long strideW, long long strideC,
    float scale, int flags)
{
  const int id = blockIdx.x;
  int z, bx, by;
  if (flags & GF_BATCH8) {
    z = id & 7;
    const int t = id >> 3;
    bx = t % nbx;
    by = t / nbx;
  } else {
    z = 0;
    by = (id & 7) + ((id >> 3) & 15) * 8;  // m-panel, XCD-pinned (128 panels)
    bx = id >> 7;
  }
  const int m0 = by * 128;
  const int n0 = bx * 128;
  if ((flags & GF_CAUSAL) && n0 > m0) return;  // tile fully above diagonal

  const BF* __restrict__ Ab = A + (size_t)z * strideA;
  const BF* __restrict__ Wb = W + (size_t)z * strideW;
  const size_t coff = (size_t)z * strideC;

  const int tid = threadIdx.x;
  const int w = tid >> 6;
  const int lane = tid & 63;
  const int lane15 = lane & 15;
  const int quad = lane >> 4;
  const int wr = w >> 1, wc = w & 1;
  const int rl = lane >> 2;
  const int clsw = ((lane & 3) ^ ((rl >> 1) & 3)) << 3;  // swizzled k-offset in elements

  __shared__ __align__(16) BF sA[2][128 * 32];
  __shared__ __align__(16) BF sW[2][128 * 32];

  v4f acc[4][4];
  {
    v4f zero = {0.f, 0.f, 0.f, 0.f};
#pragma unroll
    for (int a = 0; a < 4; ++a)
#pragma unroll
      for (int b = 0; b < 4; ++b) acc[a][b] = zero;
  }

  int Klim = K;
  if (flags & GF_KCAP) { int kc = m0 + 128; if (kc < Klim) Klim = kc; }
  const int ksteps = Klim >> 5;

  auto stage = [&](int kk, int buf) {
    const int k0 = kk << 5;
#pragma unroll
    for (int i = 0; i < 2; ++i) {
      const int r0 = w * 32 + i * 16;  // wave-uniform 16-row chunk
      async16(&sA[buf][r0 * 32], Ab + (size_t)(m0 + r0 + rl) * K + (k0 + clsw));
      async16(&sW[buf][r0 * 32], Wb + (size_t)(n0 + r0 + rl) * K + (k0 + clsw));
    }
  };

  stage(0, 0);
  const int sw = quad ^ ((lane15 >> 1) & 3);  // read-side swizzle

  for (int kk = 0; kk < ksteps; ++kk) {
    const int cur = kk & 1;
    if (kk + 1 < ksteps) {
      stage(kk + 1, cur ^ 1);                 // prefetch stays in flight across the barrier
      __builtin_amdgcn_s_waitcnt(WAIT_VM4);   // retire only this iter's 4 loads
    } else {
      __builtin_amdgcn_s_waitcnt(WAIT_VM0);
    }
    __builtin_amdgcn_s_barrier();             // buf[cur] fully populated by all waves

    v8bf aF[4], wF[4];
    const v8bf* sAv = (const v8bf*)sA[cur];
    const v8bf* sWv = (const v8bf*)sW[cur];
#pragma unroll
    for (int t = 0; t < 4; ++t) {
      aF[t] = sAv[(wr * 64 + t * 16 + lane15) * 4 + sw];
      wF[t] = sWv[(wc * 64 + t * 16 + lane15) * 4 + sw];
    }
#pragma unroll
    for (int mt = 0; mt < 4; ++mt)
#pragma unroll
      for (int nt = 0; nt < 4; ++nt)
        acc[mt][nt] = __builtin_amdgcn_mfma_f32_16x16x32_bf16(aF[mt], wF[nt], acc[mt][nt], 0, 0, 0);
    __builtin_amdgcn_s_barrier();             // all waves consumed buf[cur]
  }

  // epilogue: C/D layout col=lane&15, row=quad*4+i
#pragma unroll
  for (int mt = 0; mt < 4; ++mt) {
    const int rb = m0 + wr * 64 + mt * 16 + quad * 4;
#pragma unroll
    for (int nt = 0; nt < 4; ++nt) {
      const int cg = n0 + wc * 64 + nt * 16 + lane15;
      const float bv = bias ? bias[cg] : 0.0f;
#pragma unroll
      for (int i = 0; i < 4; ++i) {
        const int rg = rb + i;
        float v = acc[mt][nt][i] * scale + bv;
        if ((flags & GF_RELU) && v < 0.f) v = 0.f;
        if ((flags & GF_CAUSAL) && cg > rg) v = 0.f;
        if (flags & GF_QKV) {
          const BF b = __float2bfloat16(v);
          if (cg < 512) outB[(size_t)rg * 512 + cg] = b;
          else if (cg < 1024) ((BF*)outF)[(size_t)rg * 512 + (cg - 512)] = b;
          else outV[(size_t)rg * 512 + (cg - 1024)] = b;
        } else {
          if (outB) outB[coff + (size_t)rg * N + cg] = __float2bfloat16(v);
          if (outF) outF[coff + (size_t)rg * N + cg] = v;
        }
      }
    }
  }
}

// x[b,s,:] = concat(emb_table[idx[b,s]][0:448], feats[b,s,0:64]) -> bf16
__global__ void gather_kernel(const int* __restrict__ seq, const float* __restrict__ feats,
                              const float* __restrict__ emb, BF* __restrict__ xb) {
  const int row = blockIdx.x;  // b*SEQ + s
  const int t = threadIdx.x;
  const int idx = seq[row];
  BF* xr = xb + (size_t)row * DIMC;
  if (t < 224) {
    const float2 e = *(const float2*)(emb + (size_t)idx * 448 + t * 2);
    xr[t * 2] = __float2bfloat16(e.x);
    xr[t * 2 + 1] = __float2bfloat16(e.y);
  } else {
    const int j = (t - 224) * 2;
    const float2 f = *(const float2*)(feats + (size_t)row * 64 + j);
    xr[448 + j] = __float2bfloat16(f.x);
    xr[448 + j + 1] = __float2bfloat16(f.y);
  }
}

// one-shot weight prep: wb = bf16(W1|W2), wqkv = bf16 packed [2][1536][512], bqkv packed bias
__global__ void prep_kernel(const float* __restrict__ W1, const float* __restrict__ W2,
                            const float* __restrict__ Wq, const float* __restrict__ Wk,
                            const float* __restrict__ Wv, const float* __restrict__ bq,
                            const float* __restrict__ bk, const float* __restrict__ bv,
                            BF* __restrict__ wb, BF* __restrict__ wqkv, float* __restrict__ bqkv) {
  const int t = blockIdx.x * 256 + threadIdx.x;  // 655,360 threads
  const long long i = (long long)t * 4;
  float4 v;
  BF* o;
  if (i < 1048576) {  // wb: W1 | W2 (each 524,288)
    v = (i < 524288) ? *(const float4*)(W1 + i) : *(const float4*)(W2 + (i - 524288));
    o = wb + i;
  } else {            // wqkv: [l][q|k|v row][col]
    const long long j = i - 1048576;
    const int l = j >= 786432 ? 1 : 0;
    const long long rem = j - (long long)l * 786432;
    const int r = (int)(rem >> 9), c = (int)(rem & 511);
    const float* s = (r < 512) ? Wq : (r < 1024 ? Wk : Wv);
    v = *(const float4*)(s + (size_t)l * 262144 + (size_t)(r & 511) * 512 + c);
    o = wqkv + j;
  }
  o[0] = __float2bfloat16(v.x); o[1] = __float2bfloat16(v.y);
  o[2] = __float2bfloat16(v.z); o[3] = __float2bfloat16(v.w);
  if (t < 768) {  // bqkv: 3072 elems
#pragma unroll
    for (int e = t * 4; e < t * 4 + 4; ++e) {
      const int l = e / 1536, r = e % 1536;
      const float* s = (r < 512) ? bq : (r < 1024 ? bk : bv);
      bqkv[e] = s[l * 512 + (r & 511)];
    }
  }
}

// vtmp [b][s][512] bf16 -> vt [b][512][s] bf16, 64x64 LDS tiles
__global__ void transpose_kernel(const BF* __restrict__ in, BF* __restrict__ out) {
  __shared__ BF t[64][65];
  const int b = blockIdx.z;
  const int s0 = blockIdx.x * 64, d0 = blockIdx.y * 64;
  const int dx = threadIdx.x & 63, ry = threadIdx.x >> 6;  // ry in 0..3
  const BF* ib = in + ((size_t)b * SEQ + s0) * DIMC + d0;
  BF* ob = out + ((size_t)b * DIMC + d0) * SEQ + s0;
#pragma unroll
  for (int i = 0; i < 16; ++i)
    t[ry + i * 4][dx] = ib[(size_t)(ry + i * 4) * DIMC + dx];
  __syncthreads();
#pragma unroll
  for (int i = 0; i < 16; ++i)
    ob[(size_t)(ry + i * 4) * SEQ + dx] = t[dx][ry + i * 4];
}

// ---- seq-norm, 3-pass streaming ----
__global__ void seqsum_kernel(const float* __restrict__ h, float* __restrict__ part) {
  const int b = blockIdx.y, ch = blockIdx.x;  // 32 chunks of 64 rows
  const int t = threadIdx.x;
  const int half = t >> 7, cidx = t & 127;    // 128 float4-columns
  const float* hb = h + ((size_t)b * SEQ + ch * 64 + half * 32) * DIMC + cidx * 4;
  float4 sum = {0.f, 0.f, 0.f, 0.f}, sq = {0.f, 0.f, 0.f, 0.f};
#pragma unroll 4
  for (int r = 0; r < 32; ++r) {
    const float4 v = *(const float4*)(hb + (size_t)r * DIMC);
    sum.x += v.x; sum.y += v.y; sum.z += v.z; sum.w += v.w;
    sq.x += v.x * v.x; sq.y += v.y * v.y; sq.z += v.z * v.z; sq.w += v.w * v.w;
  }
  __shared__ float4 lsum[256], lsq[256];
  lsum[t] = sum; lsq[t] = sq;
  __syncthreads();
  if (t < 128) {
    const float4 s2 = lsum[t + 128], q2 = lsq[t + 128];
    sum.x += s2.x; sum.y += s2.y; sum.z += s2.z; sum.w += s2.w;
    sq.x += q2.x; sq.y += q2.y; sq.z += q2.z; sq.w += q2.w;
    float* ps = part + (size_t)(b * 32 + ch) * 1024;
    *(float4*)(ps + cidx * 4) = sum;
    *(float4*)(ps + 512 + cidx * 4) = sq;
  }
}

__global__ void seqstat_kernel(const float* __restrict__ part, float2* __restrict__ stat) {
  const int i = blockIdx.x * 256 + threadIdx.x;  // 4096 = 8*512
  const int b = i >> 9, d = i & 511;
  const float* p = part + (size_t)b * 32 * 1024 + d;
  float s = 0.f, q = 0.f;
#pragma unroll 8
  for (int c = 0; c < 32; ++c) { s += p[c * 1024]; q += p[c * 1024 + 512]; }
  const float mean = s / SEQ;
  float var = (q - mean * s) / (SEQ - 1);
  if (var < 0.f) var = 0.f;
  stat[i] = make_float2(mean, 1.0f / (sqrtf(var) + 2e-5f));
}

__global__ void seqapply_kernel(const float* __restrict__ h, const float2* __restrict__ stat,
                                BF* __restrict__ out) {
  const size_t i = ((size_t)blockIdx.x * 256 + threadIdx.x) * 4;  // 16,777,216 elems
  const int b = (int)(i >> 20);                                   // SEQ*DIMC = 2^20
  const int d = (int)(i & 511);
  const float4 v = *(const float4*)(h + i);
  const float2* sb = stat + (b << 9) + d;
  const float4 s01 = *(const float4*)(sb);
  const float4 s23 = *(const float4*)(sb + 2);
  out[i]     = __float2bfloat16((v.x - s01.x) * s01.y);
  out[i + 1] = __float2bfloat16((v.y - s01.z) * s01.w);
  out[i + 2] = __float2bfloat16((v.z - s23.x) * s23.y);
  out[i + 3] = __float2bfloat16((v.w - s23.z) * s23.w);
}

__global__ void final_kernel(const float* __restrict__ h32, float* __restrict__ out) {
  const int i = blockIdx.x * 256 + threadIdx.x;  // 0..4095
  const int b = i >> 9, d = i & 511;
  out[i] = h32[((size_t)b * SEQ + (SEQ - 1)) * DIMC + d];
}

extern "C" void kernel_launch(void* const* d_in, const int* in_sizes, int n_in,
                              void* d_out, int out_size, void* d_ws, size_t ws_size,
                              hipStream_t stream) {
  const int* seq = (const int*)d_in[0];
  const float* feats = (const float*)d_in[1];
  const float* emb = (const float*)d_in[2];
  const float* Wq = (const float*)d_in[3];
  const float* bq = (const float*)d_in[4];
  const float* Wk = (const float*)d_in[5];
  const float* bk = (const float*)d_in[6];
  const float* Wv = (const float*)d_in[7];
  const float* bv = (const float*)d_in[8];
  const float* W1 = (const float*)d_in[9];
  const float* b1 = (const float*)d_in[10];
  const float* W2 = (const float*)d_in[11];
  const float* b2 = (const float*)d_in[12];
  float* out = (float*)d_out;

  char* ws = (char*)d_ws;
  const size_t MB = 1024 * 1024;
  BF* xb = (BF*)(ws);                   // 16 MB: x bf16 (also x_next)
  BF* qb = (BF*)(ws + 16 * MB);         // 16 MB: q bf16 (also hn)
  BF* kb = (BF*)(ws + 32 * MB);         // 16 MB: k bf16 (also f1)
  BF* vt = (BF*)(ws + 48 * MB);         // 16 MB: v^T bf16 [b][d][s]
  float* h32 = (float*)(ws + 64 * MB);  // 32 MB: attention out fp32 (also final fp32)
  BF* vtmp = (BF*)(ws + 64 * MB);       // overlays h32 head: v [b][s][d] before transpose
  BF* sc = (BF*)(ws + 96 * MB);         // 64 MB: scores bf16 [b][s][n]
  BF* wb = (BF*)(ws + 160 * MB);        // 2 MB: bf16 W1,W2
  BF* wqkv = (BF*)(ws + 162 * MB);      // 3 MB: bf16 packed qkv weights [2][1536][512]
  float* bqkv = (float*)(ws + 166 * MB);// 12 KB: packed qkv bias [2][1536]
  float* part = (float*)(ws + 167 * MB);// 1 MB: seqnorm partials [8][32][2][512]
  float2* stat = (float2*)(ws + 168 * MB); // 32 KB: seqnorm mean/rstd [8][512]

  const int WT = 2 * 512 * 512;
  prep_kernel<<<2560, 256, 0, stream>>>(W1, W2, Wq, Wk, Wv, bq, bk, bv, wb, wqkv, bqkv);
  gather_kernel<<<BSZ * SEQ, 256, 0, stream>>>(seq, feats, emb, xb);

  const float attn_scale = 0.04419417382415922f;  // 1/sqrt(512)
  const dim3 blk(256);

  for (int l = 0; l < 2; ++l) {
    const BF* W1B = wb + (size_t)l * 262144;
    const BF* W2B = wb + (size_t)WT + (size_t)l * 262144;

    // fused q|k|v projection: M=16384, N=1536, K=512 (1536 blocks, XCD-pinned m-panels)
    gemm_bt<<<1536, blk, 0, stream>>>(xb, wqkv + (size_t)l * 786432, bqkv + l * 1536,
        qb, (float*)kb, vtmp, 16384, 1536, 512, 12, 0, 0, 0, 1.0f, GF_QKV);
    // coalesced v transpose -> vt [b][d][s]
    transpose_kernel<<<dim3(32, 8, 8), blk, 0, stream>>>(vtmp, vt);
    // scores = tril(q @ k^T) * scale (batch = id&7, XCD-pinned)
    gemm_bt<<<2048, blk, 0, stream>>>(qb, kb, nullptr, sc, nullptr, nullptr,
        2048, 2048, 512, 16,
        (long long)SEQ * DIMC, (long long)SEQ * DIMC, (long long)SEQ * SEQ,
        attn_scale, GF_CAUSAL | GF_BATCH8);
    // h = scores @ v (batch = id&7, K capped at diagonal)
    gemm_bt<<<512, blk, 0, stream>>>(sc, vt, nullptr, nullptr, h32, nullptr,
        2048, 512, 2048, 4,
        (long long)SEQ * SEQ, (long long)DIMC * SEQ, (long long)SEQ * DIMC,
        1.0f, GF_KCAP | GF_BATCH8);
    // seq-norm over s (3-pass streaming) -> bf16 into qb
    seqsum_kernel<<<dim3(32, 8), blk, 0, stream>>>(h32, part);
    seqstat_kernel<<<16, 256, 0, stream>>>(part, stat);
    seqapply_kernel<<<16384, 256, 0, stream>>>(h32, stat, qb);
    // ffn1 = relu(hn @ W1^T + b1) -> kb (XCD-pinned m-panels)
    gemm_bt<<<512, blk, 0, stream>>>(qb, W1B, b1 + l * 512, kb, nullptr, nullptr,
        16384, 512, 512, 4, 0, 0, 0, 1.0f, GF_RELU);
    // x_next = f1 @ W2^T + b2 -> xb (bf16); final block also fp32 -> h32
    gemm_bt<<<512, blk, 0, stream>>>(kb, W2B, b2 + l * 512, xb,
        (l == 1) ? h32 : nullptr, nullptr, 16384, 512, 512, 4, 0, 0, 0, 1.0f, 0);
  }

  final_kernel<<<16, 256, 0, stream>>>(h32, out);
}